// Round 2
// baseline (1542.635 us; speedup 1.0000x reference)
//
#include <hip/hip_runtime.h>
#include <hip/hip_bf16.h>
#include <cstdio>
#include <cstdint>

using bf16 = __hip_bfloat16;
typedef __attribute__((ext_vector_type(8))) short short8;
typedef __attribute__((ext_vector_type(4))) float floatx4;

constexpr int BB   = 16;
constexpr int NH   = 8;
constexpr int HD   = 256;
constexpr int STOT = 851;
constexpr int SPAD = 864;   // 27*32
constexpr int NQKV = 2560;  // 8*256 q + 256 k + 256 v

__device__ inline int imin(int a, int b) { return a < b ? a : b; }

// ---------------- fused fp32->bf16 conversion over many tensors ----------------
struct ConvDesc { const float* src; bf16* dst; long long n; long long cstart; };
struct ConvArgs { ConvDesc d[15]; };

__global__ __launch_bounds__(256) void convert_many(ConvArgs a) {
  long long blk = blockIdx.x;
  int i = 0;
#pragma unroll
  for (int t = 1; t < 15; ++t) if (blk >= a.d[t].cstart) i = t;
  long long base = (blk - a.d[i].cstart) * 1024 + (long long)threadIdx.x * 4;
  const float* s = a.d[i].src;
  bf16* dp = a.d[i].dst;
  long long n = a.d[i].n;
  if (base + 3 < n) {
    const float4 v = *(const float4*)(s + base);
    union { bf16 b[4]; ushort4 u; } o;
    o.b[0] = __float2bfloat16(v.x); o.b[1] = __float2bfloat16(v.y);
    o.b[2] = __float2bfloat16(v.z); o.b[3] = __float2bfloat16(v.w);
    *(ushort4*)(dp + base) = o.u;
  } else {
    for (int j = 0; j < 4; ++j)
      if (base + j < n) dp[base + j] = __float2bfloat16(s[base + j]);
  }
}

// ---------------- batched GEMM: C[bz] = A[bz] * B[bz/bdiv]^T (bf16 in, CT out) ----------------
// A: M x K (lda), Bm: N x K (ldb), C: M x N (ldc). 128x128 block tile, BK=32,
// 4 waves in 2x2, each wave 4x4 of 16x16x32 MFMA tiles.
// C addressing: C += (bz/cdiv)*sC + (bz%cdiv)*sC2  (cdiv=1,sC2=0 for plain batching)
template <typename CT> __device__ inline CT cvt_out(float x);
template <> __device__ inline float cvt_out<float>(float x) { return x; }
template <> __device__ inline bf16  cvt_out<bf16>(float x) { return __float2bfloat16(x); }

template <typename CT>
__global__ __launch_bounds__(256) void gemm_bt(
    const bf16* __restrict__ A, const bf16* __restrict__ Bm, CT* __restrict__ C,
    int M, int N, int K, int lda, int ldb, int ldc,
    long long sA, long long sB, long long sC, long long sC2, int bdiv, int cdiv)
{
  const int bz = blockIdx.z;
  A  += (long long)bz * sA;
  Bm += (long long)(bz / bdiv) * sB;
  C  += (long long)(bz / cdiv) * sC + (long long)(bz % cdiv) * sC2;
  const int m0 = blockIdx.x * 128, n0 = blockIdx.y * 128;
  __shared__ bf16 As[128][32];
  __shared__ bf16 Bs[128][32];
  const int tid  = threadIdx.x;
  const int lane = tid & 63;
  const int wv   = tid >> 6;
  const int wr   = wv >> 1, wc = wv & 1;
  const int quad = lane >> 4, l16 = lane & 15;
  floatx4 acc[4][4] = {};
  // staging: each thread loads 2x16B for A and 2x16B for B per K-tile
  const int row = tid >> 2;          // 0..63
  const int kk  = (tid & 3) * 8;     // 0,8,16,24
  const int ar1 = imin(m0 + row,      M - 1);
  const int ar2 = imin(m0 + row + 64, M - 1);
  const int br1 = imin(n0 + row,      N - 1);
  const int br2 = imin(n0 + row + 64, N - 1);
  const bf16* ap1 = A  + (long long)ar1 * lda + kk;
  const bf16* ap2 = A  + (long long)ar2 * lda + kk;
  const bf16* bp1 = Bm + (long long)br1 * ldb + kk;
  const bf16* bp2 = Bm + (long long)br2 * ldb + kk;
  const int kt = K >> 5;
  for (int t = 0; t < kt; ++t) {
    const int k0 = t * 32;
    *(short8*)(&As[row][kk])      = *(const short8*)(ap1 + k0);
    *(short8*)(&As[row + 64][kk]) = *(const short8*)(ap2 + k0);
    *(short8*)(&Bs[row][kk])      = *(const short8*)(bp1 + k0);
    *(short8*)(&Bs[row + 64][kk]) = *(const short8*)(bp2 + k0);
    __syncthreads();
    short8 af[4], bfr[4];
#pragma unroll
    for (int i = 0; i < 4; ++i) af[i]  = *(const short8*)(&As[wr*64 + i*16 + l16][quad*8]);
#pragma unroll
    for (int j = 0; j < 4; ++j) bfr[j] = *(const short8*)(&Bs[wc*64 + j*16 + l16][quad*8]);
#pragma unroll
    for (int i = 0; i < 4; ++i)
#pragma unroll
      for (int j = 0; j < 4; ++j)
        acc[i][j] = __builtin_amdgcn_mfma_f32_16x16x32_bf16(af[i], bfr[j], acc[i][j], 0, 0, 0);
    __syncthreads();
  }
#pragma unroll
  for (int i = 0; i < 4; ++i)
#pragma unroll
    for (int j = 0; j < 4; ++j)
#pragma unroll
      for (int r = 0; r < 4; ++r) {
        const int rr = m0 + wr*64 + i*16 + quad*4 + r;
        const int cc = n0 + wc*64 + j*16 + l16;
        if (rr < M && cc < N) C[(long long)rr * ldc + cc] = cvt_out<CT>(acc[i][j][r]);
      }
}

// ---------------- RoPE + scatter into padded global-seq Q/K/V layouts ----------------
// qkv: (B, sLen, 2560) bf16 rows [q(8*256) | k(256) | v(256)]
// Qb: (B*H, SPAD, 256); Kb: (B, SPAD, 256); Vb: (B, SPAD, 256)
__global__ __launch_bounds__(128) void rope_scatter(
    const bf16* __restrict__ qkv, const int* __restrict__ pos,
    bf16* __restrict__ Qb, bf16* __restrict__ Kb, bf16* __restrict__ Vb,
    int sLen, int seqOff)
{
  const int s = blockIdx.x, b = blockIdx.y;
  const int d = threadIdx.x;  // 0..127 (pair index)
  const bf16* rp = qkv + ((long long)b * sLen + s) * NQKV;
  const float p = (float)pos[b * sLen + s];
  const float invf = powf(10000.0f, -(float)d * (1.0f / 128.0f));
  float sn, cs;
  sincosf(p * invf, &sn, &cs);
  const int sg = seqOff + s;
#pragma unroll
  for (int h = 0; h < NH; ++h) {
    const float x1 = __bfloat162float(rp[h * 256 + d]);
    const float x2 = __bfloat162float(rp[h * 256 + 128 + d]);
    bf16* qd = Qb + (((long long)(b * NH + h)) * SPAD + sg) * HD;
    qd[d]       = __float2bfloat16(x1 * cs - x2 * sn);
    qd[d + 128] = __float2bfloat16(x2 * cs + x1 * sn);
  }
  {
    const float x1 = __bfloat162float(rp[2048 + d]);
    const float x2 = __bfloat162float(rp[2048 + 128 + d]);
    bf16* kd = Kb + ((long long)b * SPAD + sg) * HD;
    kd[d]       = __float2bfloat16(x1 * cs - x2 * sn);
    kd[d + 128] = __float2bfloat16(x2 * cs + x1 * sn);
    bf16* vd = Vb + ((long long)b * SPAD + sg) * HD;
    vd[d]       = rp[2304 + d];
    vd[d + 128] = rp[2304 + 128 + d];
  }
}

// ---------------- V transpose: (B, SPAD, 256) -> (B, 256, SPAD), pad cols zeroed ----------------
__global__ __launch_bounds__(256) void transpose_v(const bf16* __restrict__ Vb, bf16* __restrict__ Vt) {
  __shared__ bf16 t[32][33];
  const int b = blockIdx.z, s0 = blockIdx.x * 32, d0 = blockIdx.y * 32;
  const int tx = threadIdx.x, ty = threadIdx.y;  // 32 x 8
#pragma unroll
  for (int i = 0; i < 4; ++i) {
    const int s = s0 + ty + i * 8;
    bf16 v = __float2bfloat16(0.0f);
    if (s < STOT) v = Vb[((long long)b * SPAD + s) * HD + d0 + tx];
    t[ty + i * 8][tx] = v;
  }
  __syncthreads();
#pragma unroll
  for (int i = 0; i < 4; ++i) {
    const int d = d0 + ty + i * 8;
    Vt[((long long)b * HD + d) * SPAD + s0 + tx] = t[tx][ty + i * 8];
  }
}

// ---------------- softmax over one score row (scale, tanh-clamp, +mask) ----------------
// scores: fp32 chunk (16, SPAD, SPAD); attn: bf16 chunk (16, SPAD, SPAD)
__global__ __launch_bounds__(256) void softmax_kernel(
    const float* __restrict__ scores, const float* __restrict__ mask,
    bf16* __restrict__ attn, int chunkBase)
{
  const int q = blockIdx.x;      // 0..850
  const int bzl = blockIdx.y;    // 0..15
  const int bzg = chunkBase + bzl;
  const int b = bzg >> 3;
  const float* row  = scores + ((long long)bzl * SPAD + q) * SPAD;
  const float* mrow = mask + ((long long)b * STOT + q) * STOT;
  bf16* arow = attn + ((long long)bzl * SPAD + q) * SPAD;
  const int tid = threadIdx.x;
  __shared__ float sred[4];
  float v[4];
  float lmax = -1e30f;
#pragma unroll
  for (int ii = 0; ii < 4; ++ii) {
    const int j = tid + ii * 256;
    float x = -1e30f;
    if (j < STOT) {
      x = row[j] * 0.0625f;                 // / sqrt(256)
      x = tanhf(x * 0.02f) * 50.0f + mrow[j];
    }
    v[ii] = x;
    lmax = fmaxf(lmax, x);
  }
  for (int o = 32; o; o >>= 1) lmax = fmaxf(lmax, __shfl_down(lmax, o));
  if ((tid & 63) == 0) sred[tid >> 6] = lmax;
  __syncthreads();
  const float gmax = fmaxf(fmaxf(sred[0], sred[1]), fmaxf(sred[2], sred[3]));
  __syncthreads();
  float lsum = 0.0f;
#pragma unroll
  for (int ii = 0; ii < 4; ++ii) {
    const int j = tid + ii * 256;
    float e = 0.0f;
    if (j < STOT) e = expf(v[ii] - gmax);
    v[ii] = e;
    lsum += e;
  }
  for (int o = 32; o; o >>= 1) lsum += __shfl_down(lsum, o);
  if ((tid & 63) == 0) sred[tid >> 6] = lsum;
  __syncthreads();
  const float inv = 1.0f / (sred[0] + sred[1] + sred[2] + sred[3]);
#pragma unroll
  for (int ii = 0; ii < 4; ++ii) {
    const int j = tid + ii * 256;
    if (j < SPAD) arow[j] = __float2bfloat16(j < STOT ? v[ii] * inv : 0.0f);
  }
}

// =======================================================================================
extern "C" void kernel_launch(void* const* d_in, const int* in_sizes, int n_in,
                              void* d_out, int out_size, void* d_ws, size_t ws_size,
                              hipStream_t stream)
{
  const float* hs_in[3] = {(const float*)d_in[0], (const float*)d_in[1], (const float*)d_in[2]};
  const float* mask = (const float*)d_in[3];
  const int* pos[3] = {(const int*)d_in[4], (const int*)d_in[5], (const int*)d_in[6]};
  const float* qw[3] = {(const float*)d_in[7],  (const float*)d_in[11], (const float*)d_in[15]};
  const float* kw[3] = {(const float*)d_in[8],  (const float*)d_in[12], (const float*)d_in[16]};
  const float* vw[3] = {(const float*)d_in[9],  (const float*)d_in[13], (const float*)d_in[17]};
  const float* ow[3] = {(const float*)d_in[10], (const float*)d_in[14], (const float*)d_in[18]};
  float* out = (float*)d_out;

  const int QLs[3] = {800, 1, 50};
  const int HSs[3] = {2048, 1024, 1024};
  const int MQ[3]  = {BB * 800, BB * 1, BB * 50};
  const int offs[3] = {0, 800, 801};

  // ---- workspace carve with early/late overlay ----
  // persistent: Owb, Qb, Kb, Vb, Vt, Sc, At
  // shared region: {Xb, Wqkv, QKVr} (dead after rope_scatter) aliased with {Ob}
  char* w = (char*)d_ws;
  auto carve = [&](size_t bytes) -> char* {
    char* p = w;
    w += (bytes + 255) & ~(size_t)255;
    return p;
  };
  bf16 *Owb[3];
  for (int i = 0; i < 3; ++i) Owb[i] = (bf16*)carve((size_t)HSs[i] * 2048 * 2);
  bf16* Qb = (bf16*)carve((size_t)BB * NH * SPAD * HD * 2);
  bf16* Kb = (bf16*)carve((size_t)BB * SPAD * HD * 2);
  bf16* Vb = (bf16*)carve((size_t)BB * SPAD * HD * 2);
  bf16* Vt = (bf16*)carve((size_t)BB * SPAD * HD * 2);
  float* Sc = (float*)carve((size_t)16 * SPAD * SPAD * 4);  // per-chunk scores (16 bh slices)
  bf16* At  = (bf16*)carve((size_t)16 * SPAD * SPAD * 2);   // per-chunk attention weights
  char* sharedBase = w;
  // early overlay
  bf16 *Xb[3], *Wqkv[3], *QKVr[3];
  for (int i = 0; i < 3; ++i) Xb[i]   = (bf16*)carve((size_t)MQ[i] * HSs[i] * 2);
  for (int i = 0; i < 3; ++i) Wqkv[i] = (bf16*)carve((size_t)NQKV * HSs[i] * 2);
  for (int i = 0; i < 3; ++i) QKVr[i] = (bf16*)carve((size_t)MQ[i] * NQKV * 2);
  char* earlyEnd = w;
  // late overlay (aliases the early region)
  bf16* Ob = (bf16*)sharedBase;                              // (B, 851, 2048) bf16
  char* lateEnd = sharedBase + (size_t)BB * STOT * NH * HD * 2;
  const size_t need = (size_t)((earlyEnd > lateEnd ? earlyEnd : lateEnd) - (char*)d_ws);
  fprintf(stderr, "[jointattn] ws_size=%zu need=%zu\n", ws_size, need);
  if (need > ws_size) {
    fprintf(stderr, "[jointattn] INSUFFICIENT WORKSPACE — aborting launch\n");
    return;
  }

  // ---- 1. fused conversions (15 tensors) ----
  ConvArgs ca;
  long long cs = 0;
  int ci = 0;
  auto addconv = [&](const float* s, bf16* d, long long n) {
    ca.d[ci].src = s; ca.d[ci].dst = d; ca.d[ci].n = n; ca.d[ci].cstart = cs;
    cs += (n + 1023) / 1024;
    ++ci;
  };
  for (int i = 0; i < 3; ++i) addconv(hs_in[i], Xb[i], (long long)MQ[i] * HSs[i]);
  for (int i = 0; i < 3; ++i) {
    addconv(qw[i], Wqkv[i],                         2048LL * HSs[i]);
    addconv(kw[i], Wqkv[i] + 2048LL * HSs[i],       256LL * HSs[i]);
    addconv(vw[i], Wqkv[i] + 2304LL * HSs[i],       256LL * HSs[i]);
  }
  for (int i = 0; i < 3; ++i) addconv(ow[i], Owb[i], (long long)HSs[i] * 2048);
  convert_many<<<dim3((unsigned)cs), 256, 0, stream>>>(ca);

  auto gemm_b = [&](const bf16* A, const bf16* Bm, bf16* C, int M, int N, int K,
                    int lda, int ldb, int ldc, long long sA, long long sB,
                    long long sC, long long sC2, int bdiv, int cdiv, int nbz) {
    dim3 g((M + 127) / 128, (N + 127) / 128, nbz);
    gemm_bt<bf16><<<g, 256, 0, stream>>>(A, Bm, C, M, N, K, lda, ldb, ldc, sA, sB, sC, sC2, bdiv, cdiv);
  };
  auto gemm_f = [&](const bf16* A, const bf16* Bm, float* C, int M, int N, int K,
                    int lda, int ldb, int ldc, long long sA, long long sB,
                    long long sC, long long sC2, int bdiv, int cdiv, int nbz) {
    dim3 g((M + 127) / 128, (N + 127) / 128, nbz);
    gemm_bt<float><<<g, 256, 0, stream>>>(A, Bm, C, M, N, K, lda, ldb, ldc, sA, sB, sC, sC2, bdiv, cdiv);
  };

  // ---- 2. QKV projections (one fused N=2560 GEMM per stream) ----
  for (int i = 0; i < 3; ++i)
    gemm_b(Xb[i], Wqkv[i], QKVr[i], MQ[i], NQKV, HSs[i], HSs[i], HSs[i], NQKV,
           0, 0, 0, 0, 1, 1, 1);

  // ---- 3. RoPE + scatter ----
  for (int i = 0; i < 3; ++i)
    rope_scatter<<<dim3(QLs[i], BB), 128, 0, stream>>>(QKVr[i], pos[i], Qb, Kb, Vb, QLs[i], offs[i]);

  // ---- 4. V transpose ----
  transpose_v<<<dim3(SPAD / 32, HD / 32, BB), dim3(32, 8), 0, stream>>>(Vb, Vt);

  // ---- 5. attention in 8 chunks of 16 (b,h) slices; PV writes bf16 directly
  //         into the gathered (B, 851, 2048) layout ----
  for (int c = 0; c < 8; ++c) {
    const bf16* Qc = Qb + (long long)c * 16 * SPAD * HD;
    const bf16* Kc = Kb + (long long)c * 2 * SPAD * HD;
    gemm_f(Qc, Kc, Sc, STOT, SPAD, HD, HD, HD, SPAD,
           (long long)SPAD * HD, (long long)SPAD * HD,
           (long long)SPAD * SPAD, 0, NH, 1, 16);
    softmax_kernel<<<dim3(STOT, 16), 256, 0, stream>>>(Sc, mask, At, c * 16);
    const bf16* Vc = Vt + (long long)c * 2 * HD * SPAD;
    bf16* Oc = Ob + (long long)c * 2 * STOT * (NH * HD);   // chunk covers 2 batches
    gemm_b(At, Vc, Oc, STOT, HD, SPAD, SPAD, SPAD, NH * HD,
           (long long)SPAD * SPAD, (long long)HD * SPAD,
           (long long)STOT * NH * HD, (long long)HD, NH, NH, 16);
  }

  // ---- 6. output projections, straight into d_out ----
  const long long outOff[3] = {0,
                               (long long)BB * 800 * 2048,
                               (long long)BB * 800 * 2048 + (long long)BB * 1 * 1024};
  for (int i = 0; i < 3; ++i)
    gemm_f(Ob + (long long)offs[i] * 2048, Owb[i], out + outOff[i],
           QLs[i], HSs[i], 2048, 2048, 2048, HSs[i],
           (long long)STOT * 2048, 0, (long long)QLs[i] * HSs[i], 0, 1, 1, BB);
}

// Round 3
// 1359.057 us; speedup vs baseline: 1.1351x; 1.1351x over previous
//
#include <hip/hip_runtime.h>
#include <hip/hip_bf16.h>
#include <cstdio>
#include <cstdint>

using bf16 = __hip_bfloat16;
typedef __attribute__((ext_vector_type(8))) short short8;
typedef __attribute__((ext_vector_type(4))) float floatx4;

constexpr int BB   = 16;
constexpr int NH   = 8;
constexpr int HD   = 256;
constexpr int STOT = 851;
constexpr int SPAD = 864;   // 27*32
constexpr int NQKV = 2560;  // 8*256 q + 256 k + 256 v
constexpr int CH   = 32;    // bh-slices per attention chunk (4 chunks of 32)

__device__ inline int imin(int a, int b) { return a < b ? a : b; }

// async global->LDS DMA, 16B per lane; LDS dest = wave-uniform base + lane*16
__device__ inline void gl_lds16(const bf16* g, bf16* l) {
  __builtin_amdgcn_global_load_lds((const __attribute__((address_space(1))) void*)g,
                                   (__attribute__((address_space(3))) void*)l, 16, 0, 0);
}

// ---------------- fused fp32->bf16 conversion over many tensors ----------------
struct ConvDesc { const float* src; bf16* dst; long long n; long long cstart; };
struct ConvArgs { ConvDesc d[15]; };

__global__ __launch_bounds__(256) void convert_many(ConvArgs a) {
  long long blk = blockIdx.x;
  int i = 0;
#pragma unroll
  for (int t = 1; t < 15; ++t) if (blk >= a.d[t].cstart) i = t;
  long long base = (blk - a.d[i].cstart) * 1024 + (long long)threadIdx.x * 4;
  const float* s = a.d[i].src;
  bf16* dp = a.d[i].dst;
  long long n = a.d[i].n;
  if (base + 3 < n) {
    const float4 v = *(const float4*)(s + base);
    union { bf16 b[4]; ushort4 u; } o;
    o.b[0] = __float2bfloat16(v.x); o.b[1] = __float2bfloat16(v.y);
    o.b[2] = __float2bfloat16(v.z); o.b[3] = __float2bfloat16(v.w);
    *(ushort4*)(dp + base) = o.u;
  } else {
    for (int j = 0; j < 4; ++j)
      if (base + j < n) dp[base + j] = __float2bfloat16(s[base + j]);
  }
}

// ---------------- batched GEMM: C[bz] = A[bz] * B[bz/bdiv]^T (bf16 in, CT out) ----------------
// A: M x K (lda), Bm: N x K (ldb), C: M x N (ldc). 128x128 block tile, BK=32,
// 4 waves in 2x2, each wave 4x4 of 16x16x32 MFMA tiles.
// Staging via global_load_lds width=16 (m97 structure).
// C addressing: C += (bz/cdiv)*sC + (bz%cdiv)*sC2
template <typename CT> __device__ inline CT cvt_out(float x);
template <> __device__ inline float cvt_out<float>(float x) { return x; }
template <> __device__ inline bf16  cvt_out<bf16>(float x) { return __float2bfloat16(x); }

template <typename CT>
__global__ __launch_bounds__(256) void gemm_bt(
    const bf16* __restrict__ A, const bf16* __restrict__ Bm, CT* __restrict__ C,
    int M, int N, int K, int lda, int ldb, int ldc,
    long long sA, long long sB, long long sC, long long sC2, int bdiv, int cdiv)
{
  const int bz = blockIdx.z;
  A  += (long long)bz * sA;
  Bm += (long long)(bz / bdiv) * sB;
  C  += (long long)(bz / cdiv) * sC + (long long)(bz % cdiv) * sC2;
  const int m0 = blockIdx.x * 128, n0 = blockIdx.y * 128;
  __shared__ bf16 As[128][32];
  __shared__ bf16 Bs[128][32];
  const int tid  = threadIdx.x;
  const int lane = tid & 63;
  const int wv   = tid >> 6;
  const int wr   = wv >> 1, wc = wv & 1;
  const int quad = lane >> 4, l16 = lane & 15;
  floatx4 acc[4][4] = {};
  // staging: thread tid covers A/B rows (tid>>2) and (tid>>2)+64, k-offset (tid&3)*8.
  // Per wave this is LDS-contiguous: addr = wv*1024 + lane*16  (global_load_lds layout)
  const int row = tid >> 2;          // 0..63
  const int kk  = (tid & 3) * 8;     // 0,8,16,24
  const int ar1 = imin(m0 + row,      M - 1);
  const int ar2 = imin(m0 + row + 64, M - 1);
  const int br1 = imin(n0 + row,      N - 1);
  const int br2 = imin(n0 + row + 64, N - 1);
  const bf16* ap1 = A  + (long long)ar1 * lda + kk;
  const bf16* ap2 = A  + (long long)ar2 * lda + kk;
  const bf16* bp1 = Bm + (long long)br1 * ldb + kk;
  const bf16* bp2 = Bm + (long long)br2 * ldb + kk;
  bf16* ldsA1 = &As[wv * 16][0];
  bf16* ldsA2 = &As[64 + wv * 16][0];
  bf16* ldsB1 = &Bs[wv * 16][0];
  bf16* ldsB2 = &Bs[64 + wv * 16][0];
  const int kt = K >> 5;
  for (int t = 0; t < kt; ++t) {
    const int k0 = t * 32;
    gl_lds16(ap1 + k0, ldsA1);
    gl_lds16(ap2 + k0, ldsA2);
    gl_lds16(bp1 + k0, ldsB1);
    gl_lds16(bp2 + k0, ldsB2);
    __syncthreads();
    short8 af[4], bfr[4];
#pragma unroll
    for (int i = 0; i < 4; ++i) af[i]  = *(const short8*)(&As[wr*64 + i*16 + l16][quad*8]);
#pragma unroll
    for (int j = 0; j < 4; ++j) bfr[j] = *(const short8*)(&Bs[wc*64 + j*16 + l16][quad*8]);
#pragma unroll
    for (int i = 0; i < 4; ++i)
#pragma unroll
      for (int j = 0; j < 4; ++j)
        acc[i][j] = __builtin_amdgcn_mfma_f32_16x16x32_bf16(af[i], bfr[j], acc[i][j], 0, 0, 0);
    __syncthreads();
  }
#pragma unroll
  for (int i = 0; i < 4; ++i)
#pragma unroll
    for (int j = 0; j < 4; ++j)
#pragma unroll
      for (int r = 0; r < 4; ++r) {
        const int rr = m0 + wr*64 + i*16 + quad*4 + r;
        const int cc = n0 + wc*64 + j*16 + l16;
        if (rr < M && cc < N) C[(long long)rr * ldc + cc] = cvt_out<CT>(acc[i][j][r]);
      }
}

// ---------------- RoPE + scatter into padded global-seq Q/K/V layouts ----------------
__global__ __launch_bounds__(128) void rope_scatter(
    const bf16* __restrict__ qkv, const int* __restrict__ pos,
    bf16* __restrict__ Qb, bf16* __restrict__ Kb, bf16* __restrict__ Vb,
    int sLen, int seqOff)
{
  const int s = blockIdx.x, b = blockIdx.y;
  const int d = threadIdx.x;  // 0..127 (pair index)
  const bf16* rp = qkv + ((long long)b * sLen + s) * NQKV;
  const float p = (float)pos[b * sLen + s];
  const float invf = powf(10000.0f, -(float)d * (1.0f / 128.0f));
  float sn, cs;
  sincosf(p * invf, &sn, &cs);
  const int sg = seqOff + s;
#pragma unroll
  for (int h = 0; h < NH; ++h) {
    const float x1 = __bfloat162float(rp[h * 256 + d]);
    const float x2 = __bfloat162float(rp[h * 256 + 128 + d]);
    bf16* qd = Qb + (((long long)(b * NH + h)) * SPAD + sg) * HD;
    qd[d]       = __float2bfloat16(x1 * cs - x2 * sn);
    qd[d + 128] = __float2bfloat16(x2 * cs + x1 * sn);
  }
  {
    const float x1 = __bfloat162float(rp[2048 + d]);
    const float x2 = __bfloat162float(rp[2048 + 128 + d]);
    bf16* kd = Kb + ((long long)b * SPAD + sg) * HD;
    kd[d]       = __float2bfloat16(x1 * cs - x2 * sn);
    kd[d + 128] = __float2bfloat16(x2 * cs + x1 * sn);
    bf16* vd = Vb + ((long long)b * SPAD + sg) * HD;
    vd[d]       = rp[2304 + d];
    vd[d + 128] = rp[2304 + 128 + d];
  }
}

// ---------------- V transpose: (B, SPAD, 256) -> (B, 256, SPAD), pad cols zeroed ----------------
__global__ __launch_bounds__(256) void transpose_v(const bf16* __restrict__ Vb, bf16* __restrict__ Vt) {
  __shared__ bf16 t[32][33];
  const int b = blockIdx.z, s0 = blockIdx.x * 32, d0 = blockIdx.y * 32;
  const int tx = threadIdx.x, ty = threadIdx.y;  // 32 x 8
#pragma unroll
  for (int i = 0; i < 4; ++i) {
    const int s = s0 + ty + i * 8;
    bf16 v = __float2bfloat16(0.0f);
    if (s < STOT) v = Vb[((long long)b * SPAD + s) * HD + d0 + tx];
    t[ty + i * 8][tx] = v;
  }
  __syncthreads();
#pragma unroll
  for (int i = 0; i < 4; ++i) {
    const int d = d0 + ty + i * 8;
    Vt[((long long)b * HD + d) * SPAD + s0 + tx] = t[tx][ty + i * 8];
  }
}

// ---------------- softmax over one score row (scale, tanh-clamp, +mask) ----------------
// scores: fp32 chunk (CH, SPAD, SPAD); attn: bf16 chunk (CH, SPAD, SPAD)
__global__ __launch_bounds__(256) void softmax_kernel(
    const float* __restrict__ scores, const float* __restrict__ mask,
    bf16* __restrict__ attn, int chunkBase)
{
  const int q = blockIdx.x;      // 0..850
  const int bzl = blockIdx.y;    // 0..CH-1
  const int bzg = chunkBase + bzl;
  const int b = bzg >> 3;
  const float* row  = scores + ((long long)bzl * SPAD + q) * SPAD;
  const float* mrow = mask + ((long long)b * STOT + q) * STOT;
  bf16* arow = attn + ((long long)bzl * SPAD + q) * SPAD;
  const int tid = threadIdx.x;
  __shared__ float sred[4];
  float v[4];
  float lmax = -1e30f;
#pragma unroll
  for (int ii = 0; ii < 4; ++ii) {
    const int j = tid + ii * 256;
    float x = -1e30f;
    if (j < STOT) {
      x = row[j] * 0.0625f;                 // / sqrt(256)
      x = tanhf(x * 0.02f) * 50.0f + mrow[j];
    }
    v[ii] = x;
    lmax = fmaxf(lmax, x);
  }
  for (int o = 32; o; o >>= 1) lmax = fmaxf(lmax, __shfl_down(lmax, o));
  if ((tid & 63) == 0) sred[tid >> 6] = lmax;
  __syncthreads();
  const float gmax = fmaxf(fmaxf(sred[0], sred[1]), fmaxf(sred[2], sred[3]));
  __syncthreads();
  float lsum = 0.0f;
#pragma unroll
  for (int ii = 0; ii < 4; ++ii) {
    const int j = tid + ii * 256;
    float e = 0.0f;
    if (j < STOT) e = expf(v[ii] - gmax);
    v[ii] = e;
    lsum += e;
  }
  for (int o = 32; o; o >>= 1) lsum += __shfl_down(lsum, o);
  if ((tid & 63) == 0) sred[tid >> 6] = lsum;
  __syncthreads();
  const float inv = 1.0f / (sred[0] + sred[1] + sred[2] + sred[3]);
#pragma unroll
  for (int ii = 0; ii < 4; ++ii) {
    const int j = tid + ii * 256;
    if (j < SPAD) arow[j] = __float2bfloat16(j < STOT ? v[ii] * inv : 0.0f);
  }
}

// =======================================================================================
extern "C" void kernel_launch(void* const* d_in, const int* in_sizes, int n_in,
                              void* d_out, int out_size, void* d_ws, size_t ws_size,
                              hipStream_t stream)
{
  const float* hs_in[3] = {(const float*)d_in[0], (const float*)d_in[1], (const float*)d_in[2]};
  const float* mask = (const float*)d_in[3];
  const int* pos[3] = {(const int*)d_in[4], (const int*)d_in[5], (const int*)d_in[6]};
  const float* qw[3] = {(const float*)d_in[7],  (const float*)d_in[11], (const float*)d_in[15]};
  const float* kw[3] = {(const float*)d_in[8],  (const float*)d_in[12], (const float*)d_in[16]};
  const float* vw[3] = {(const float*)d_in[9],  (const float*)d_in[13], (const float*)d_in[17]};
  const float* ow[3] = {(const float*)d_in[10], (const float*)d_in[14], (const float*)d_in[18]};
  float* out = (float*)d_out;

  const int QLs[3] = {800, 1, 50};
  const int HSs[3] = {2048, 1024, 1024};
  const int MQ[3]  = {BB * 800, BB * 1, BB * 50};
  const int offs[3] = {0, 800, 801};

  // ---- workspace carve with early/late overlay ----
  char* w = (char*)d_ws;
  auto carve = [&](size_t bytes) -> char* {
    char* p = w;
    w += (bytes + 255) & ~(size_t)255;
    return p;
  };
  bf16 *Owb[3];
  for (int i = 0; i < 3; ++i) Owb[i] = (bf16*)carve((size_t)HSs[i] * 2048 * 2);
  bf16* Qb = (bf16*)carve((size_t)BB * NH * SPAD * HD * 2);
  bf16* Kb = (bf16*)carve((size_t)BB * SPAD * HD * 2);
  bf16* Vb = (bf16*)carve((size_t)BB * SPAD * HD * 2);
  bf16* Vt = (bf16*)carve((size_t)BB * SPAD * HD * 2);
  float* Sc = (float*)carve((size_t)CH * SPAD * SPAD * 4);  // per-chunk scores
  bf16* At  = (bf16*)carve((size_t)CH * SPAD * SPAD * 2);   // per-chunk attention weights
  char* sharedBase = w;
  // early overlay
  bf16 *Xb[3], *Wqkv[3], *QKVr[3];
  for (int i = 0; i < 3; ++i) Xb[i]   = (bf16*)carve((size_t)MQ[i] * HSs[i] * 2);
  for (int i = 0; i < 3; ++i) Wqkv[i] = (bf16*)carve((size_t)NQKV * HSs[i] * 2);
  for (int i = 0; i < 3; ++i) QKVr[i] = (bf16*)carve((size_t)MQ[i] * NQKV * 2);
  char* earlyEnd = w;
  // late overlay (aliases the early region)
  bf16* Ob = (bf16*)sharedBase;                              // (B, 851, 2048) bf16
  char* lateEnd = sharedBase + (size_t)BB * STOT * NH * HD * 2;
  const size_t need = (size_t)((earlyEnd > lateEnd ? earlyEnd : lateEnd) - (char*)d_ws);
  fprintf(stderr, "[jointattn] ws_size=%zu need=%zu\n", ws_size, need);
  if (need > ws_size) {
    fprintf(stderr, "[jointattn] INSUFFICIENT WORKSPACE — aborting launch\n");
    return;
  }

  // ---- 1. fused conversions (15 tensors) ----
  ConvArgs ca;
  long long cs = 0;
  int ci = 0;
  auto addconv = [&](const float* s, bf16* d, long long n) {
    ca.d[ci].src = s; ca.d[ci].dst = d; ca.d[ci].n = n; ca.d[ci].cstart = cs;
    cs += (n + 1023) / 1024;
    ++ci;
  };
  for (int i = 0; i < 3; ++i) addconv(hs_in[i], Xb[i], (long long)MQ[i] * HSs[i]);
  for (int i = 0; i < 3; ++i) {
    addconv(qw[i], Wqkv[i],                         2048LL * HSs[i]);
    addconv(kw[i], Wqkv[i] + 2048LL * HSs[i],       256LL * HSs[i]);
    addconv(vw[i], Wqkv[i] + 2304LL * HSs[i],       256LL * HSs[i]);
  }
  for (int i = 0; i < 3; ++i) addconv(ow[i], Owb[i], (long long)HSs[i] * 2048);
  convert_many<<<dim3((unsigned)cs), 256, 0, stream>>>(ca);

  auto gemm_b = [&](const bf16* A, const bf16* Bm, bf16* C, int M, int N, int K,
                    int lda, int ldb, int ldc, long long sA, long long sB,
                    long long sC, long long sC2, int bdiv, int cdiv, int nbz) {
    dim3 g((M + 127) / 128, (N + 127) / 128, nbz);
    gemm_bt<bf16><<<g, 256, 0, stream>>>(A, Bm, C, M, N, K, lda, ldb, ldc, sA, sB, sC, sC2, bdiv, cdiv);
  };
  auto gemm_f = [&](const bf16* A, const bf16* Bm, float* C, int M, int N, int K,
                    int lda, int ldb, int ldc, long long sA, long long sB,
                    long long sC, long long sC2, int bdiv, int cdiv, int nbz) {
    dim3 g((M + 127) / 128, (N + 127) / 128, nbz);
    gemm_bt<float><<<g, 256, 0, stream>>>(A, Bm, C, M, N, K, lda, ldb, ldc, sA, sB, sC, sC2, bdiv, cdiv);
  };

  // ---- 2. QKV projections (one fused N=2560 GEMM per stream) ----
  for (int i = 0; i < 3; ++i)
    gemm_b(Xb[i], Wqkv[i], QKVr[i], MQ[i], NQKV, HSs[i], HSs[i], HSs[i], NQKV,
           0, 0, 0, 0, 1, 1, 1);

  // ---- 3. RoPE + scatter ----
  for (int i = 0; i < 3; ++i)
    rope_scatter<<<dim3(QLs[i], BB), 128, 0, stream>>>(QKVr[i], pos[i], Qb, Kb, Vb, QLs[i], offs[i]);

  // ---- 4. V transpose ----
  transpose_v<<<dim3(SPAD / 32, HD / 32, BB), dim3(32, 8), 0, stream>>>(Vb, Vt);

  // ---- 5. attention in 4 chunks of CH=32 (b,h) slices; PV writes bf16 directly
  //         into the gathered (B, 851, 2048) layout ----
  for (int c = 0; c < 128 / CH; ++c) {
    const bf16* Qc = Qb + (long long)c * CH * SPAD * HD;
    const bf16* Kc = Kb + (long long)c * (CH / NH) * SPAD * HD;
    gemm_f(Qc, Kc, Sc, STOT, SPAD, HD, HD, HD, SPAD,
           (long long)SPAD * HD, (long long)SPAD * HD,
           (long long)SPAD * SPAD, 0, NH, 1, CH);
    softmax_kernel<<<dim3(STOT, CH), 256, 0, stream>>>(Sc, mask, At, c * CH);
    const bf16* Vc = Vt + (long long)c * (CH / NH) * HD * SPAD;
    bf16* Oc = Ob + (long long)c * (CH / NH) * STOT * (NH * HD);
    gemm_b(At, Vc, Oc, STOT, HD, SPAD, SPAD, SPAD, NH * HD,
           (long long)SPAD * SPAD, (long long)HD * SPAD,
           (long long)STOT * NH * HD, (long long)HD, NH, NH, CH);
  }

  // ---- 6. output projections, straight into d_out ----
  const long long outOff[3] = {0,
                               (long long)BB * 800 * 2048,
                               (long long)BB * 800 * 2048 + (long long)BB * 1 * 1024};
  for (int i = 0; i < 3; ++i)
    gemm_f(Ob + (long long)offs[i] * 2048, Owb[i], out + outOff[i],
           QLs[i], HSs[i], 2048, 2048, 2048, HSs[i],
           (long long)STOT * 2048, 0, (long long)QLs[i] * HSs[i], 0, 1, 1, BB);
}